// Round 18
// baseline (64.569 us; speedup 1.0000x reference)
//
#include <hip/hip_runtime.h>
#include <math.h>

#define TOKENS 16384
#define HID    2048
#define NCH    16
#define TPB    128         // tokens per block-group (2 K-split blocks share it)

typedef float f4 __attribute__((ext_vector_type(4)));
typedef short s8v __attribute__((ext_vector_type(8)));

// ws byte layout:
//   part [0, 8MB)            fp32 [2][16384][64] partial logits
//   bp   [8388608, +128KB)   float[256][128] aux partials
//   g2   [8519680, +16KB)    stage-1 loss partials [32][128]
#define WS_BP  8388608
#define WS_G2  8519680

__device__ __forceinline__ unsigned short bf16rne(float x) {
  unsigned u = __float_as_uint(x);
  return (unsigned short)((u + 0x7FFFu + ((u >> 16) & 1u)) >> 16);
}

__device__ __forceinline__ void gl16(const void* g, const void* l) {
  __builtin_amdgcn_global_load_lds(
      (const __attribute__((address_space(1))) void*)g,
      (__attribute__((address_space(3))) void*)l, 16, 0, 0);
}

#define BARK(N) { asm volatile("s_waitcnt vmcnt(" #N ") lgkmcnt(0)" ::: "memory"); \
  __builtin_amdgcn_sched_barrier(0); __builtin_amdgcn_s_barrier(); \
  __builtin_amdgcn_sched_barrier(0); }

__global__ __launch_bounds__(512, 1) void k_main(const float* __restrict__ hid,
                                                 const float* __restrict__ gw,
                                                 float* __restrict__ part) {
  // 3 buffers * 49152B: A fp32 [128 tok][256B] (32KB) + B fp32 [64 e][256B] (16KB)
  __shared__ __align__(16) char lds[147456];
  const int tid = threadIdx.x, wave = tid >> 6, lane = tid & 63;
  const int l15 = lane & 15, ks = lane >> 4;
  const int tg = blockIdx.x >> 1, kq = blockIdx.x & 1;   // token-group, K-half
  const int tok0 = tg * TPB;

  // ---- staging sources (64B-line-local granule permutation; LDS dest linear) ----
  const char* hb = (const char*)hid;
  size_t asrc[4]; int adst[4];
  #pragma unroll
  for (int j = 0; j < 4; ++j) {
    int u = j * 512 + tid;
    int row = u >> 4, g = u & 15;
    asrc[j] = (size_t)(tok0 + row) * 8192 + (size_t)kq * 4096
            + (size_t)((g ^ (row & 3)) << 4);
    adst[j] = u * 16;
  }
  // B: raw fp32 weights [64 e][256B per chunk] (split to planes in-reg at compute)
  const char* gwb = (const char*)gw;
  size_t bsrc[2]; int bdst[2];
  #pragma unroll
  for (int j = 0; j < 2; ++j) {
    int v = j * 512 + tid;
    int e = v >> 4, g = v & 15;
    bsrc[j] = (size_t)e * 8192 + (size_t)kq * 4096 + (size_t)((g ^ (e & 3)) << 4);
    bdst[j] = 32768 + v * 16;
  }

  f4 acc[4] = {{0.f,0.f,0.f,0.f},{0.f,0.f,0.f,0.f},{0.f,0.f,0.f,0.f},{0.f,0.f,0.f,0.f}};
  const int arow = wave * 16 + l15, asw = arow & 3;

  auto stage = [&](int c, int bufb) {
    #pragma unroll
    for (int j = 0; j < 4; ++j)
      gl16(hb + asrc[j] + (size_t)c * 256, lds + bufb + adst[j]);
    #pragma unroll
    for (int j = 0; j < 2; ++j)
      gl16(gwb + bsrc[j] + (size_t)c * 256, lds + bufb + bdst[j]);
  };

  auto compute = [&](int bufb) {
    #pragma unroll
    for (int s = 0; s < 2; ++s) {
      int g0 = (s * 8 + ks * 2) ^ asw;
      int g1 = (s * 8 + ks * 2 + 1) ^ asw;
      f4 a0 = *(const f4*)(lds + bufb + arow * 256 + g0 * 16);
      f4 a1 = *(const f4*)(lds + bufb + arow * 256 + g1 * 16);
      float av[8] = {a0.x, a0.y, a0.z, a0.w, a1.x, a1.y, a1.z, a1.w};
      unsigned short p1[8], p2[8];
      #pragma unroll
      for (int i = 0; i < 8; ++i) {
        unsigned short h = bf16rne(av[i]);
        p1[i] = h;
        float r = av[i] - __uint_as_float((unsigned)h << 16);
        p2[i] = bf16rne(r);
      }
      s8v af1 = *(s8v*)p1;
      s8v af2 = *(s8v*)p2;
      #pragma unroll
      for (int nj = 0; nj < 4; ++nj) {
        int e = nj * 16 + l15;
        int bsw = e & 3;
        int h0 = (s * 8 + ks * 2) ^ bsw;
        int h1 = (s * 8 + ks * 2 + 1) ^ bsw;
        f4 b0 = *(const f4*)(lds + bufb + 32768 + e * 256 + h0 * 16);
        f4 b1 = *(const f4*)(lds + bufb + 32768 + e * 256 + h1 * 16);
        float bv[8] = {b0.x, b0.y, b0.z, b0.w, b1.x, b1.y, b1.z, b1.w};
        unsigned short q1[8], q2[8];
        #pragma unroll
        for (int i = 0; i < 8; ++i) {
          unsigned short h = bf16rne(bv[i]);
          q1[i] = h;
          float r = bv[i] - __uint_as_float((unsigned)h << 16);
          q2[i] = bf16rne(r);
        }
        s8v bw1 = *(s8v*)q1;
        s8v bw2 = *(s8v*)q2;
        acc[nj] = __builtin_amdgcn_mfma_f32_16x16x32_bf16(af1, bw1, acc[nj], 0, 0, 0);
        acc[nj] = __builtin_amdgcn_mfma_f32_16x16x32_bf16(af1, bw2, acc[nj], 0, 0, 0);
        acc[nj] = __builtin_amdgcn_mfma_f32_16x16x32_bf16(af2, bw1, acc[nj], 0, 0, 0);
      }
    }
  };

  stage(0, 0);
  stage(1, 49152);
  BARK(6);

  for (int c = 0; c < NCH; ++c) {
    const int bufb = (c % 3) * 49152;
    if (c + 2 < NCH) {
      stage(c + 2, ((c + 2) % 3) * 49152);
      compute(bufb);
      BARK(6);
    } else if (c + 1 < NCH) {
      compute(bufb);
      BARK(0);
    } else {
      compute(bufb);
    }
  }

  // ---- write partial logits: part[kq][token][expert] ----
  #pragma unroll
  for (int nj = 0; nj < 4; ++nj) {
    int e = nj * 16 + l15;
    #pragma unroll
    for (int r = 0; r < 4; ++r) {
      int tl = wave * 16 + ks * 4 + r;
      part[((size_t)kq * TOKENS + (size_t)(tok0 + tl)) * 64 + e] = acc[nj][r];
    }
  }
}

// sum the two K-halves, softmax/top-2; aux partials via LDS transpose
__global__ __launch_bounds__(64) void k_finish(const float* __restrict__ part,
                                               float* __restrict__ out,
                                               float* __restrict__ bp) {
  __shared__ float pr[64][65];   // [token][expert], stride 65 -> conflict-free
  __shared__ float cnt[64];
  const int lane = threadIdx.x;
  const int t = blockIdx.x * 64 + lane;

  cnt[lane] = 0.f;

  float lg[64];
  const float* p0 = part + (size_t)t * 64;
  const float* p1 = part + (size_t)TOKENS * 64 + (size_t)t * 64;
  #pragma unroll
  for (int e = 0; e < 64; e += 4) {
    f4 a = *(const f4*)(p0 + e);
    f4 b = *(const f4*)(p1 + e);
    lg[e]     = a.x + b.x;
    lg[e + 1] = a.y + b.y;
    lg[e + 2] = a.z + b.z;
    lg[e + 3] = a.w + b.w;
  }

  float m = lg[0];
  #pragma unroll
  for (int e = 1; e < 64; ++e) m = fmaxf(m, lg[e]);
  float s = 0.f;
  #pragma unroll
  for (int e = 0; e < 64; ++e) { lg[e] = __expf(lg[e] - m); s += lg[e]; }
  const float inv = 1.f / s;

  // top-2 on exp values (monotone); strict '>' == lax.top_k tie-break
  float b0 = -1.f, b1 = -1.f;
  int i0 = 0, i1 = 0;
  #pragma unroll
  for (int e = 0; e < 64; ++e) {
    float p = lg[e];
    if (p > b0)      { b1 = b0; i1 = i0; b0 = p; i0 = e; }
    else if (p > b1) { b1 = p; i1 = e; }
  }
  const float rs = 1.f / (b0 + b1);
  out[(size_t)t * 2]                  = b0 * rs;
  out[(size_t)t * 2 + 1]              = b1 * rs;
  out[(size_t)TOKENS * 2 + t * 2]     = (float)i0;
  out[(size_t)TOKENS * 2 + t * 2 + 1] = (float)i1;

  // aux partials: write softmax probs row, count top-2 via LDS atomics
  #pragma unroll
  for (int e = 0; e < 64; ++e) pr[lane][e] = lg[e] * inv;
  atomicAdd(&cnt[i0], 1.f);
  atomicAdd(&cnt[i1], 1.f);
  __syncthreads();

  float sp = 0.f;
  #pragma unroll 8
  for (int tt = 0; tt < 64; ++tt) sp += pr[tt][lane];   // expert-column sum
  bp[(size_t)blockIdx.x * 128 + lane]      = sp;
  bp[(size_t)blockIdx.x * 128 + 64 + lane] = cnt[lane];
}

__global__ __launch_bounds__(128) void k_loss1(const float* __restrict__ bp,
                                               float* __restrict__ g2) {
  float s = 0.f;
  #pragma unroll 4
  for (int j = 0; j < 8; ++j)
    s += bp[(size_t)(blockIdx.x * 8 + j) * 128 + threadIdx.x];
  g2[(size_t)blockIdx.x * 128 + threadIdx.x] = s;
}

__global__ __launch_bounds__(128) void k_loss2(const float* __restrict__ g2,
                                               float* __restrict__ out) {
  const int tid = threadIdx.x;
  float s = 0.f;
  #pragma unroll 8
  for (int j = 0; j < 32; ++j) s += g2[(size_t)j * 128 + tid];
  __shared__ float red[128];
  red[tid] = s;
  __syncthreads();
  if (tid < 64) {
    float v = red[tid] * red[64 + tid];   // sumprob_e * count_e
    #pragma unroll
    for (int d = 1; d < 64; d <<= 1) v += __shfl_xor(v, d);
    if (tid == 0)
      out[(size_t)TOKENS * 4] = 0.01f * 64.f * v / (16384.f * 16384.f);
  }
}

extern "C" void kernel_launch(void* const* d_in, const int* in_sizes, int n_in,
                              void* d_out, int out_size, void* d_ws, size_t ws_size,
                              hipStream_t stream) {
  (void)in_sizes; (void)n_in; (void)out_size; (void)ws_size;
  const float* hid = (const float*)d_in[0];
  const float* gw  = (const float*)d_in[1];
  float* out = (float*)d_out;
  char* ws = (char*)d_ws;
  float* part  = (float*)ws;
  float* bp    = (float*)(ws + WS_BP);
  float* g2    = (float*)(ws + WS_G2);

  k_main  <<<256, 512, 0, stream>>>(hid, gw, part);
  k_finish<<<256, 64, 0, stream>>>(part, out, bp);
  k_loss1 <<<32, 128, 0, stream>>>(bp, g2);
  k_loss2 <<<1, 128, 0, stream>>>(g2, out);
}

// Round 19
// 46.199 us; speedup vs baseline: 1.3976x; 1.3976x over previous
//
#include <hip/hip_runtime.h>
#include <math.h>

#define TOKENS 16384
#define HID    2048
#define NCH    16
#define TPB    128         // tokens per block-group (2 K-split blocks share it)

typedef float f4 __attribute__((ext_vector_type(4)));
typedef short s8v __attribute__((ext_vector_type(8)));

// ws byte layout:
//   w1   [0, 256KB)          bf16 plane1 [64][2048]   (dead after k_main)
//   w2   [256KB, 512KB)      bf16 plane2 [64][2048]   (dead after k_main)
//   part [512KB, 512KB+8MB)  fp32 [2][16384][64] partial logits
//   bp   [0, 128KB)          reuses w1 region (written by k_finish)
#define WS_W2   262144
#define WS_PART 524288

__device__ __forceinline__ unsigned short bf16rne(float x) {
  unsigned u = __float_as_uint(x);
  return (unsigned short)((u + 0x7FFFu + ((u >> 16) & 1u)) >> 16);
}

__device__ __forceinline__ void gl16(const void* g, const void* l) {
  __builtin_amdgcn_global_load_lds(
      (const __attribute__((address_space(1))) void*)g,
      (__attribute__((address_space(3))) void*)l, 16, 0, 0);
}

#define BARK(N) { asm volatile("s_waitcnt vmcnt(" #N ") lgkmcnt(0)" ::: "memory"); \
  __builtin_amdgcn_sched_barrier(0); __builtin_amdgcn_s_barrier(); \
  __builtin_amdgcn_sched_barrier(0); }

// fp32 weights -> two bf16 planes (w ~= w1 + w2, residual ~2^-18)
__global__ __launch_bounds__(256) void k_pack(const float* __restrict__ gw,
                                              unsigned short* __restrict__ w1,
                                              unsigned short* __restrict__ w2) {
  int gid = blockIdx.x * 256 + threadIdx.x;   // 16384 threads * 8 els
  int m = gid * 8;
  f4 a = *(const f4*)(gw + m);
  f4 b = *(const f4*)(gw + m + 4);
  float av[8] = {a.x, a.y, a.z, a.w, b.x, b.y, b.z, b.w};
  unsigned short p1[8], p2[8];
  #pragma unroll
  for (int i = 0; i < 8; ++i) {
    unsigned short h = bf16rne(av[i]);
    p1[i] = h;
    float r = av[i] - __uint_as_float((unsigned)h << 16);
    p2[i] = bf16rne(r);
  }
  *(s8v*)(w1 + m) = *(s8v*)p1;
  *(s8v*)(w2 + m) = *(s8v*)p2;
}

__global__ __launch_bounds__(512, 1) void k_main(const float* __restrict__ hid,
                                                 const unsigned short* __restrict__ w1,
                                                 const unsigned short* __restrict__ w2,
                                                 float* __restrict__ part) {
  // 3 buffers * 49152B: A fp32 [128 tok][256B] (32KB) + w1 [64 e][128B] (8KB) + w2 (8KB)
  __shared__ __align__(16) char lds[147456];
  const int tid = threadIdx.x, wave = tid >> 6, lane = tid & 63;
  const int l15 = lane & 15, ks = lane >> 4;
  const int tg = blockIdx.x >> 1, kq = blockIdx.x & 1;   // token-group, K-half
  const int tok0 = tg * TPB;

  // ---- staging sources (64B-line-local granule permutation; LDS dest linear) ----
  const char* hb = (const char*)hid;
  size_t asrc[4]; int adst[4];
  #pragma unroll
  for (int j = 0; j < 4; ++j) {
    int u = j * 512 + tid;
    int row = u >> 4, g = u & 15;
    asrc[j] = (size_t)(tok0 + row) * 8192 + (size_t)kq * 4096
            + (size_t)((g ^ (row & 3)) << 4);
    adst[j] = u * 16;
  }
  // B: waves 0-3 stage w1, waves 4-7 stage w2 (2 granules/thread)
  const char* wpb = (tid < 256) ? (const char*)w1 : (const char*)w2;
  const int bdst0 = (tid < 256) ? 32768 : 40960;
  const int tt = tid & 255;
  size_t bsrc[2]; int bdst[2];
  #pragma unroll
  for (int j = 0; j < 2; ++j) {
    int v = j * 256 + tt;
    int e = v >> 3, g = v & 7;
    bsrc[j] = (size_t)e * 4096 + (size_t)kq * 2048 + (size_t)((g ^ (e & 3)) << 4);
    bdst[j] = bdst0 + v * 16;
  }

  f4 acc[4] = {{0.f,0.f,0.f,0.f},{0.f,0.f,0.f,0.f},{0.f,0.f,0.f,0.f},{0.f,0.f,0.f,0.f}};
  const int arow = wave * 16 + l15, asw = arow & 3;

  auto stage = [&](int c, int bufb) {
    #pragma unroll
    for (int j = 0; j < 4; ++j)
      gl16(hb + asrc[j] + (size_t)c * 256, lds + bufb + adst[j]);
    #pragma unroll
    for (int j = 0; j < 2; ++j)
      gl16(wpb + bsrc[j] + (size_t)c * 128, lds + bufb + bdst[j]);
  };

  auto compute = [&](int bufb) {
    #pragma unroll
    for (int s = 0; s < 2; ++s) {
      int g0 = (s * 8 + ks * 2) ^ asw;
      int g1 = (s * 8 + ks * 2 + 1) ^ asw;
      f4 a0 = *(const f4*)(lds + bufb + arow * 256 + g0 * 16);
      f4 a1 = *(const f4*)(lds + bufb + arow * 256 + g1 * 16);
      float av[8] = {a0.x, a0.y, a0.z, a0.w, a1.x, a1.y, a1.z, a1.w};
      unsigned short p1[8], p2[8];
      #pragma unroll
      for (int i = 0; i < 8; ++i) {
        unsigned short h = bf16rne(av[i]);
        p1[i] = h;
        float r = av[i] - __uint_as_float((unsigned)h << 16);
        p2[i] = bf16rne(r);
      }
      s8v af1 = *(s8v*)p1;
      s8v af2 = *(s8v*)p2;
      #pragma unroll
      for (int nj = 0; nj < 4; ++nj) {
        int e = nj * 16 + l15;
        int g = (s * 4 + ks) ^ (e & 3);
        s8v bw1 = *(const s8v*)(lds + bufb + 32768 + e * 128 + g * 16);
        s8v bw2 = *(const s8v*)(lds + bufb + 40960 + e * 128 + g * 16);
        acc[nj] = __builtin_amdgcn_mfma_f32_16x16x32_bf16(af1, bw1, acc[nj], 0, 0, 0);
        acc[nj] = __builtin_amdgcn_mfma_f32_16x16x32_bf16(af1, bw2, acc[nj], 0, 0, 0);
        acc[nj] = __builtin_amdgcn_mfma_f32_16x16x32_bf16(af2, bw1, acc[nj], 0, 0, 0);
      }
    }
  };

  stage(0, 0);
  stage(1, 49152);
  BARK(6);

  for (int c = 0; c < NCH; ++c) {
    const int bufb = (c % 3) * 49152;
    if (c + 2 < NCH) {
      stage(c + 2, ((c + 2) % 3) * 49152);
      compute(bufb);
      BARK(6);
    } else if (c + 1 < NCH) {
      compute(bufb);
      BARK(0);
    } else {
      compute(bufb);
    }
  }

  // ---- write partial logits: part[kq][token][expert] ----
  #pragma unroll
  for (int nj = 0; nj < 4; ++nj) {
    int e = nj * 16 + l15;
    #pragma unroll
    for (int r = 0; r < 4; ++r) {
      int tl = wave * 16 + ks * 4 + r;
      part[((size_t)kq * TOKENS + (size_t)(tok0 + tl)) * 64 + e] = acc[nj][r];
    }
  }
}

// sum the two K-halves, softmax/top-2; aux partials via LDS transpose
__global__ __launch_bounds__(64) void k_finish(const float* __restrict__ part,
                                               float* __restrict__ out,
                                               float* __restrict__ bp) {
  __shared__ float pr[64][65];   // [token][expert], stride 65 -> conflict-free
  __shared__ float cnt[64];
  const int lane = threadIdx.x;
  const int t = blockIdx.x * 64 + lane;

  cnt[lane] = 0.f;

  float lg[64];
  const float* p0 = part + (size_t)t * 64;
  const float* p1 = part + (size_t)TOKENS * 64 + (size_t)t * 64;
  #pragma unroll
  for (int e = 0; e < 64; e += 4) {
    f4 a = *(const f4*)(p0 + e);
    f4 b = *(const f4*)(p1 + e);
    lg[e]     = a.x + b.x;
    lg[e + 1] = a.y + b.y;
    lg[e + 2] = a.z + b.z;
    lg[e + 3] = a.w + b.w;
  }

  float m = lg[0];
  #pragma unroll
  for (int e = 1; e < 64; ++e) m = fmaxf(m, lg[e]);
  float s = 0.f;
  #pragma unroll
  for (int e = 0; e < 64; ++e) { lg[e] = __expf(lg[e] - m); s += lg[e]; }
  const float inv = 1.f / s;

  // top-2 on exp values (monotone); strict '>' == lax.top_k tie-break
  float b0 = -1.f, b1 = -1.f;
  int i0 = 0, i1 = 0;
  #pragma unroll
  for (int e = 0; e < 64; ++e) {
    float p = lg[e];
    if (p > b0)      { b1 = b0; i1 = i0; b0 = p; i0 = e; }
    else if (p > b1) { b1 = p; i1 = e; }
  }
  const float rs = 1.f / (b0 + b1);
  out[(size_t)t * 2]                  = b0 * rs;
  out[(size_t)t * 2 + 1]              = b1 * rs;
  out[(size_t)TOKENS * 2 + t * 2]     = (float)i0;
  out[(size_t)TOKENS * 2 + t * 2 + 1] = (float)i1;

  // aux partials: write softmax probs row, count top-2 via LDS atomics
  #pragma unroll
  for (int e = 0; e < 64; ++e) pr[lane][e] = lg[e] * inv;
  atomicAdd(&cnt[i0], 1.f);
  atomicAdd(&cnt[i1], 1.f);
  __syncthreads();

  float sp = 0.f;
  #pragma unroll 8
  for (int tt = 0; tt < 64; ++tt) sp += pr[tt][lane];   // expert-column sum
  bp[(size_t)blockIdx.x * 128 + lane]      = sp;
  bp[(size_t)blockIdx.x * 128 + 64 + lane] = cnt[lane];
}

// fused loss reduction: one block, 1024 threads, parallel strided loads
__global__ __launch_bounds__(1024) void k_loss(const float* __restrict__ bp,
                                               float* __restrict__ out) {
  __shared__ float partial[8][128];
  const int tid = threadIdx.x;
  const int col = tid & 127, grp = tid >> 7;   // 8 groups x 128 cols
  float s = 0.f;
  #pragma unroll 4
  for (int j = 0; j < 32; ++j)
    s += bp[(size_t)(grp + j * 8) * 128 + col];
  partial[grp][col] = s;
  __syncthreads();
  if (tid < 128) {
    float t = 0.f;
    #pragma unroll
    for (int g = 0; g < 8; ++g) t += partial[g][tid];
    partial[0][tid] = t;
  }
  __syncthreads();
  if (tid < 64) {
    float v = partial[0][tid] * partial[0][64 + tid];   // sumprob_e * count_e
    #pragma unroll
    for (int d = 1; d < 64; d <<= 1) v += __shfl_xor(v, d);
    if (tid == 0)
      out[(size_t)TOKENS * 4] = 0.01f * 64.f * v / (16384.f * 16384.f);
  }
}

extern "C" void kernel_launch(void* const* d_in, const int* in_sizes, int n_in,
                              void* d_out, int out_size, void* d_ws, size_t ws_size,
                              hipStream_t stream) {
  (void)in_sizes; (void)n_in; (void)out_size; (void)ws_size;
  const float* hid = (const float*)d_in[0];
  const float* gw  = (const float*)d_in[1];
  float* out = (float*)d_out;
  char* ws = (char*)d_ws;
  unsigned short* w1 = (unsigned short*)ws;            // dead after k_main
  unsigned short* w2 = (unsigned short*)(ws + WS_W2);  // dead after k_main
  float* part  = (float*)(ws + WS_PART);
  float* bp    = (float*)ws;                           // reuses w1 region

  k_pack  <<<64, 256, 0, stream>>>(gw, w1, w2);
  k_main  <<<256, 512, 0, stream>>>(hid, w1, w2, part);
  k_finish<<<256, 64, 0, stream>>>(part, out, bp);
  k_loss  <<<1, 1024, 0, stream>>>(bp, out);
}